// Round 4
// baseline (1617.496 us; speedup 1.0000x reference)
//
#include <hip/hip_runtime.h>
#include <math.h>

// ---------------------------------------------------------------------------
// GConvNet via dst-bucketed edge partition + LDS aggregation.
// R4: in-place counting sort of each dst-bucket's edges by src-super
// (src>>14, 64 supers). All agg blocks sweep supers in the same order, so
// concurrent gathers target a ~512KB slab of y -> L2-resident -> the
// per-XCD L2-fill fabric (the measured R3 wall) sees y ~once per sweep.
//
// ws layout (dwords):
//   pd    [NBKT*CAP]            @ 0
//   cs    [NBKT]                @ PDW          (zeroed)
//   cd    [NBKT]                @ PDW+1024     (zeroed)
//   gsum  [4G]                  @ PDW+2048     (zeroed)
//   gcnt  [G]                   @ PDW+6144     (zeroed)
//   onorm [n]                   @ PDW+7168
//   ybuf  [8n]  (y1 then y2)    @ PDW+7168+n
//   hbuf  [8n]  (h1 then h2)    @ PDW+7168+9n
// ---------------------------------------------------------------------------

#define BSHIFT 10
#define BMASK  1023u
#define NBKT   1024
#define CAP    17408u
#define NSUP   64            // src supers: src>>14 (1M nodes -> 62 used)
#define RPT    ((CAP + 511) / 512)   // 34 edges per thread in reorder
#define EPT    32            // edges per thread in partition kernels
#define PTH    1024          // threads per partition block
#define CHUNK  (PTH * EPT)   // 32768 edges per block

// ---- partition src (keys only, ushort payload) ----------------------------
__global__ __launch_bounds__(PTH) void k_part_src(const int* __restrict__ src,
                                                  unsigned short* __restrict__ ps,
                                                  unsigned int* __restrict__ cur,
                                                  int n_edges) {
    __shared__ unsigned int hist[NBKT];
    __shared__ unsigned int base[NBKT];
    const int tid = threadIdx.x;
    const int e0 = blockIdx.x * CHUNK;
    for (int i = tid; i < NBKT; i += PTH) hist[i] = 0;
    __syncthreads();
    unsigned int sv[EPT];
    unsigned int rk[EPT];
#pragma unroll
    for (int k = 0; k < EPT; ++k) {
        int e = e0 + k * PTH + tid;
        if (e < n_edges) {
            unsigned int s = (unsigned int)src[e];
            sv[k] = s;
            rk[k] = atomicAdd(&hist[s >> BSHIFT], 1u);
        } else {
            sv[k] = 0xFFFFFFFFu;
        }
    }
    __syncthreads();
    if (tid < NBKT) base[tid] = atomicAdd(&cur[tid], hist[tid]);
    __syncthreads();
#pragma unroll
    for (int k = 0; k < EPT; ++k) {
        if (sv[k] != 0xFFFFFFFFu) {
            unsigned int b = sv[k] >> BSHIFT;
            unsigned int pos = b * CAP + base[b] + rk[k];
            ps[pos] = (unsigned short)(sv[k] & BMASK);
        }
    }
}

// ---- partition dst with packed (src,dstlow) payload -----------------------
__global__ __launch_bounds__(PTH) void k_part_dst(const int* __restrict__ src,
                                                  const int* __restrict__ dst,
                                                  unsigned int* __restrict__ pd,
                                                  unsigned int* __restrict__ cur,
                                                  int n_edges) {
    __shared__ unsigned int hist[NBKT];
    __shared__ unsigned int base[NBKT];
    const int tid = threadIdx.x;
    const int e0 = blockIdx.x * CHUNK;
    for (int i = tid; i < NBKT; i += PTH) hist[i] = 0;
    __syncthreads();
    unsigned int wv[EPT];  // packed (src<<10)|(dst&1023)
    unsigned int br[EPT];  // packed (bucket<<20)|rank, 0xFFFFFFFF = invalid
#pragma unroll
    for (int k = 0; k < EPT; ++k) {
        int e = e0 + k * PTH + tid;
        if (e < n_edges) {
            unsigned int d = (unsigned int)dst[e];
            unsigned int s = (unsigned int)src[e];
            unsigned int b = d >> BSHIFT;
            wv[k] = (s << BSHIFT) | (d & BMASK);
            unsigned int r = atomicAdd(&hist[b], 1u);
            br[k] = (b << 20) | r;
        } else {
            br[k] = 0xFFFFFFFFu;
        }
    }
    __syncthreads();
    if (tid < NBKT) base[tid] = atomicAdd(&cur[tid], hist[tid]);
    __syncthreads();
#pragma unroll
    for (int k = 0; k < EPT; ++k) {
        if (br[k] != 0xFFFFFFFFu) {
            unsigned int b = br[k] >> 20;
            unsigned int r = br[k] & 0xFFFFFu;
            pd[b * CAP + base[b] + r] = wv[k];
        }
    }
}

// ---- in-place counting sort of one bucket's edges by src-super ------------
// w = (src<<10)|dstlow ; super = w>>24 == src>>14 (< 62).
__global__ __launch_bounds__(512) void k_reorder(unsigned int* __restrict__ pd,
                                                 const unsigned int* __restrict__ cur) {
    __shared__ unsigned int hist[NSUP];
    __shared__ unsigned int curs[NSUP];
    const int b = blockIdx.x, tid = threadIdx.x;
    if (tid < NSUP) hist[tid] = 0;
    __syncthreads();
    const unsigned int n = cur[b];
    const unsigned int base = (unsigned int)b * CAP;
    unsigned int rv[RPT];
#pragma unroll
    for (int k = 0; k < RPT; ++k) {
        unsigned int i = (unsigned int)k * 512u + (unsigned int)tid;
        rv[k] = 0xFFFFFFFFu;
        if (i < n) {
            rv[k] = pd[base + i];
            atomicAdd(&hist[rv[k] >> 24], 1u);
        }
    }
    __syncthreads();   // all reads + hist done before scan/writes
    if (tid == 0) {
        unsigned int run = 0;
        for (int s = 0; s < NSUP; ++s) { curs[s] = run; run += hist[s]; }
    }
    __syncthreads();
#pragma unroll
    for (int k = 0; k < RPT; ++k) {
        if (rv[k] != 0xFFFFFFFFu) {
            unsigned int pos = atomicAdd(&curs[rv[k] >> 24], 1u);
            pd[base + pos] = rv[k];
        }
    }
}

// ---- out-degree histogram per src bucket -> onorm -------------------------
__global__ __launch_bounds__(512) void k_deg_src(const unsigned short* __restrict__ ps,
                                                 const unsigned int* __restrict__ cur,
                                                 float* __restrict__ onorm, int n_nodes) {
    __shared__ unsigned int cnt[1 << BSHIFT];
    const int b = blockIdx.x, tid = threadIdx.x;
    for (int i = tid; i < (1 << BSHIFT); i += 512) cnt[i] = 0;
    __syncthreads();
    const unsigned int n = cur[b];
    const unsigned int base = (unsigned int)b * CAP;
    const unsigned int nfull = n & ~4095u;  // 512 thr * 8 keys
    for (unsigned int i0 = 0; i0 < nfull; i0 += 4096) {
        uint4 p = *(const uint4*)(ps + base + i0 + (unsigned int)tid * 8u);
        unsigned int w[4] = {p.x, p.y, p.z, p.w};
#pragma unroll
        for (int k = 0; k < 4; ++k) {
            atomicAdd(&cnt[w[k] & 0xFFFFu], 1u);
            atomicAdd(&cnt[w[k] >> 16], 1u);
        }
    }
    for (unsigned int i = nfull + tid; i < n; i += 512) atomicAdd(&cnt[ps[base + i]], 1u);
    __syncthreads();
    for (int r = tid; r < (1 << BSHIFT); r += 512) {
        int node = (b << BSHIFT) + r;
        if (node < n_nodes) onorm[node] = rsqrtf(fmaxf((float)cnt[r], 1.0f));
    }
}

// ---- y1 = (feat @ W1) * onorm  (10 -> 8) ----------------------------------
__global__ void k_node1(const float* __restrict__ feat, const float* __restrict__ W1,
                        const float* __restrict__ onorm, float* __restrict__ y1,
                        int n_nodes) {
    int i = blockIdx.x * blockDim.x + threadIdx.x;
    if (i >= n_nodes) return;
    float on = onorm[i];
    const float* fr = feat + (size_t)i * 10;
    float f[10];
#pragma unroll
    for (int k = 0; k < 10; ++k) f[k] = fr[k];
    float acc[8];
#pragma unroll
    for (int j = 0; j < 8; ++j) acc[j] = 0.0f;
#pragma unroll
    for (int k = 0; k < 10; ++k)
#pragma unroll
        for (int j = 0; j < 8; ++j) acc[j] = fmaf(f[k], W1[k * 8 + j], acc[j]);
    float4* yo = (float4*)(y1 + (size_t)i * 8);
    yo[0] = make_float4(acc[0] * on, acc[1] * on, acc[2] * on, acc[3] * on);
    yo[1] = make_float4(acc[4] * on, acc[5] * on, acc[6] * on, acc[7] * on);
}

// ---- per-bucket aggregation: h = relu(inn * sum(y[src]) + bias) -----------
// Edges pre-sorted by src-super: all co-resident blocks sweep y slab-by-slab.
template <int F>
__global__ __launch_bounds__(512) void k_agg_lds(const unsigned int* __restrict__ pd,
                                                 const unsigned int* __restrict__ cur,
                                                 const float* __restrict__ y,
                                                 const float* __restrict__ bias,
                                                 float* __restrict__ h, int n_nodes) {
    __shared__ float acc[(1 << BSHIFT) * F];
    __shared__ unsigned int cnt[1 << BSHIFT];
    const int b = blockIdx.x, tid = threadIdx.x;
    for (int i = tid; i < (1 << BSHIFT) * F; i += 512) acc[i] = 0.0f;
    for (int i = tid; i < (1 << BSHIFT); i += 512) cnt[i] = 0;
    __syncthreads();
    const unsigned int n = cur[b];
    const unsigned int base = (unsigned int)b * CAP;
    const unsigned int nfull = n & ~4095u;  // 512 thr * 8 slots
    for (unsigned int i0 = 0; i0 < nfull; i0 += 4096) {
        const unsigned int s0 = base + i0 + (unsigned int)tid * 8u;
        uint4 p0 = *(const uint4*)(pd + s0);
        uint4 p1 = *(const uint4*)(pd + s0 + 4);
        unsigned int w[8] = {p0.x, p0.y, p0.z, p0.w, p1.x, p1.y, p1.z, p1.w};
        float4 v0[8];
        float4 v1[8];
#pragma unroll
        for (int k = 0; k < 8; ++k) {
            const float* yr = y + (size_t)(w[k] >> BSHIFT) * F;
            v0[k] = *(const float4*)yr;
            if (F == 8) v1[k] = *(const float4*)(yr + 4);
        }
#pragma unroll
        for (int k = 0; k < 8; ++k) {
            unsigned int d = w[k] & BMASK;
            atomicAdd(&cnt[d], 1u);
            atomicAdd(&acc[d * F + 0], v0[k].x);
            atomicAdd(&acc[d * F + 1], v0[k].y);
            atomicAdd(&acc[d * F + 2], v0[k].z);
            atomicAdd(&acc[d * F + 3], v0[k].w);
            if (F == 8) {
                atomicAdd(&acc[d * F + 4], v1[k].x);
                atomicAdd(&acc[d * F + 5], v1[k].y);
                atomicAdd(&acc[d * F + 6], v1[k].z);
                atomicAdd(&acc[d * F + 7], v1[k].w);
            }
        }
    }
    for (unsigned int i = nfull + tid; i < n; i += 512) {
        unsigned int w = pd[base + i];
        unsigned int d = w & BMASK;
        unsigned int s = w >> BSHIFT;
        atomicAdd(&cnt[d], 1u);
        const float* yr = y + (size_t)s * F;
        float4 q0 = *(const float4*)yr;
        atomicAdd(&acc[d * F + 0], q0.x);
        atomicAdd(&acc[d * F + 1], q0.y);
        atomicAdd(&acc[d * F + 2], q0.z);
        atomicAdd(&acc[d * F + 3], q0.w);
        if (F == 8) {
            float4 q1 = *(const float4*)(yr + 4);
            atomicAdd(&acc[d * F + 4], q1.x);
            atomicAdd(&acc[d * F + 5], q1.y);
            atomicAdd(&acc[d * F + 6], q1.z);
            atomicAdd(&acc[d * F + 7], q1.w);
        }
    }
    __syncthreads();
    for (int r = tid; r < (1 << BSHIFT); r += 512) {
        int node = (b << BSHIFT) + r;
        if (node >= n_nodes) continue;
        float inn = rsqrtf(fmaxf((float)cnt[r], 1.0f));
        float4 o0;
        o0.x = fmaxf(fmaf(acc[r * F + 0], inn, bias[0]), 0.0f);
        o0.y = fmaxf(fmaf(acc[r * F + 1], inn, bias[1]), 0.0f);
        o0.z = fmaxf(fmaf(acc[r * F + 2], inn, bias[2]), 0.0f);
        o0.w = fmaxf(fmaf(acc[r * F + 3], inn, bias[3]), 0.0f);
        ((float4*)(h + (size_t)node * F))[0] = o0;
        if (F == 8) {
            float4 o1;
            o1.x = fmaxf(fmaf(acc[r * F + 4], inn, bias[4]), 0.0f);
            o1.y = fmaxf(fmaf(acc[r * F + 5], inn, bias[5]), 0.0f);
            o1.z = fmaxf(fmaf(acc[r * F + 6], inn, bias[6]), 0.0f);
            o1.w = fmaxf(fmaf(acc[r * F + 7], inn, bias[7]), 0.0f);
            ((float4*)(h + (size_t)node * F))[1] = o1;
        }
    }
}

// ---- y2 = (h1 @ W2) * onorm  (8 -> 4) -------------------------------------
__global__ void k_node2(const float* __restrict__ h1, const float* __restrict__ W2,
                        const float* __restrict__ onorm, float* __restrict__ y2,
                        int n_nodes) {
    int i = blockIdx.x * blockDim.x + threadIdx.x;
    if (i >= n_nodes) return;
    float on = onorm[i];
    const float4* hr = (const float4*)(h1 + (size_t)i * 8);
    float4 a0 = hr[0];
    float4 a1 = hr[1];
    float hv[8] = {a0.x, a0.y, a0.z, a0.w, a1.x, a1.y, a1.z, a1.w};
    float acc[4] = {0.0f, 0.0f, 0.0f, 0.0f};
#pragma unroll
    for (int k = 0; k < 8; ++k)
#pragma unroll
        for (int j = 0; j < 4; ++j) acc[j] = fmaf(hv[k], W2[k * 4 + j], acc[j]);
    ((float4*)(y2 + (size_t)i * 4))[0] =
        make_float4(acc[0] * on, acc[1] * on, acc[2] * on, acc[3] * on);
}

// ---- per-graph pooling (gid sorted -> wave-segmented reduce) --------------
__global__ void k_pool(const float* __restrict__ h2, const int* __restrict__ gid,
                       float* __restrict__ gsum, float* __restrict__ gcnt, int n_nodes) {
    int i = blockIdx.x * blockDim.x + threadIdx.x;
    int lane = threadIdx.x & 63;
    int g = -1;
    float v0 = 0.f, v1 = 0.f, v2 = 0.f, v3 = 0.f, c = 0.f;
    if (i < n_nodes) {
        float4 a = ((const float4*)(h2 + (size_t)i * 4))[0];
        v0 = a.x; v1 = a.y; v2 = a.z; v3 = a.w;
        c = 1.0f;
        g = gid[i];
    }
#pragma unroll
    for (int s = 1; s < 64; s <<= 1) {
        int go   = __shfl_down(g, s);
        float t0 = __shfl_down(v0, s);
        float t1 = __shfl_down(v1, s);
        float t2 = __shfl_down(v2, s);
        float t3 = __shfl_down(v3, s);
        float tc = __shfl_down(c, s);
        if (lane + s < 64 && go == g) {
            v0 += t0; v1 += t1; v2 += t2; v3 += t3; c += tc;
        }
    }
    int gp = __shfl_up(g, 1);
    bool head = (lane == 0) || (gp != g);
    if (g >= 0 && head) {
        unsafeAtomicAdd(&gsum[g * 4 + 0], v0);
        unsafeAtomicAdd(&gsum[g * 4 + 1], v1);
        unsafeAtomicAdd(&gsum[g * 4 + 2], v2);
        unsafeAtomicAdd(&gsum[g * 4 + 3], v3);
        unsafeAtomicAdd(&gcnt[g], c);
    }
}

__global__ void k_final(const float* __restrict__ gsum, const float* __restrict__ gcnt,
                        const float* __restrict__ Wo, const float* __restrict__ bo,
                        float* __restrict__ out, int n_graphs) {
    int i = blockIdx.x * blockDim.x + threadIdx.x;
    if (i >= n_graphs) return;
    float inv = 1.0f / fmaxf(gcnt[i], 1.0f);
    float z = bo[0];
#pragma unroll
    for (int j = 0; j < 4; ++j) z = fmaf(gsum[i * 4 + j] * inv, Wo[j], z);
    out[i] = 1.0f / (1.0f + expf(-z));
}

extern "C" void kernel_launch(void* const* d_in, const int* in_sizes, int n_in,
                              void* d_out, int out_size, void* d_ws, size_t ws_size,
                              hipStream_t stream) {
    const float* feat = (const float*)d_in[0];
    const int*   src  = (const int*)d_in[1];
    const int*   dst  = (const int*)d_in[2];
    const int*   gid  = (const int*)d_in[3];
    const float* W1   = (const float*)d_in[4];
    const float* b1   = (const float*)d_in[5];
    const float* W2   = (const float*)d_in[6];
    const float* b2   = (const float*)d_in[7];
    const float* Wo   = (const float*)d_in[8];
    const float* bo   = (const float*)d_in[9];
    float* out = (float*)d_out;

    const int n_nodes  = in_sizes[0] / 10;
    const int n_edges  = in_sizes[1];
    const int n_graphs = out_size;
    const int nbk_used = (n_nodes + (1 << BSHIFT) - 1) >> BSHIFT;

    unsigned int* ws32 = (unsigned int*)d_ws;
    const size_t PDW = (size_t)NBKT * CAP;
    unsigned int*   pd    = ws32;
    unsigned short* ps    = (unsigned short*)ws32;   // aliases pd (time-multiplexed)
    unsigned int*   cs    = ws32 + PDW;
    unsigned int*   cd    = cs + NBKT;
    float*          gsum  = (float*)(cd + NBKT);
    float*          gcnt  = gsum + 4 * (size_t)n_graphs;
    float*          onorm = gcnt + n_graphs;
    float*          ybuf  = onorm + n_nodes;
    float*          hbuf  = ybuf + 8 * (size_t)n_nodes;

    hipMemsetAsync(cs, 0, (2 * NBKT + 5 * (size_t)n_graphs) * sizeof(unsigned int), stream);

    const int nchunk = (n_edges + CHUNK - 1) / CHUNK;
    const int B = 256;

    k_part_src<<<nchunk, PTH, 0, stream>>>(src, ps, cs, n_edges);
    k_deg_src<<<nbk_used, 512, 0, stream>>>(ps, cs, onorm, n_nodes);
    k_part_dst<<<nchunk, PTH, 0, stream>>>(src, dst, pd, cd, n_edges);
    k_reorder<<<nbk_used, 512, 0, stream>>>(pd, cd);
    k_node1<<<(n_nodes + B - 1) / B, B, 0, stream>>>(feat, W1, onorm, ybuf, n_nodes);
    k_agg_lds<8><<<nbk_used, 512, 0, stream>>>(pd, cd, ybuf, b1, hbuf, n_nodes);
    k_node2<<<(n_nodes + B - 1) / B, B, 0, stream>>>(hbuf, W2, onorm, ybuf, n_nodes);
    k_agg_lds<4><<<nbk_used, 512, 0, stream>>>(pd, cd, ybuf, b2, hbuf, n_nodes);
    k_pool<<<(n_nodes + B - 1) / B, B, 0, stream>>>(hbuf, gid, gsum, gcnt, n_nodes);
    k_final<<<(n_graphs + B - 1) / B, B, 0, stream>>>(gsum, gcnt, Wo, bo, out, n_graphs);
}

// Round 5
// 1599.952 us; speedup vs baseline: 1.0110x; 1.0110x over previous
//
#include <hip/hip_runtime.h>
#include <hip/hip_fp16.h>
#include <math.h>

// ---------------------------------------------------------------------------
// GConvNet via dst-bucketed edge partition + LDS aggregation.
// R5: (1) XOR-rotate swizzle on LDS accumulator addresses -- R4 showed the
// wall is LDS atomic bank serialization (acc[d*F+j] uses only 32/F banks);
// swizzle spreads to all 32. (2) fp16 y rows: one 16B/8B gather per edge.
// (3) in-degree computed once in agg1, reused by agg2 via global innorm.
//
// ws layout (dwords):
//   pd     [NBKT*CAP]  @ 0
//   cs     [NBKT]      cd [NBKT]  gsum [4G]  gcnt [G]   (zeroed)
//   onorm  [n]
//   innorm [n]
//   ybuf   [4n]   y1 = half8/node (4n dw); y2 = half4/node (2n dw, aliased)
//   hbuf   [8n]   h1 = f32x8/node; h2 = f32x4/node aliases first 4n
// ---------------------------------------------------------------------------

#define BSHIFT 10
#define BMASK  1023u
#define NBKT   1024
#define CAP    17408u
#define NSUP   64
#define RPT    ((CAP + 511) / 512)
#define EPT    32
#define PTH    1024
#define CHUNK  (PTH * EPT)

__device__ inline unsigned int pack2(float a, float b) {
    __half2 h = __floats2half2_rn(a, b);
    return *reinterpret_cast<unsigned int*>(&h);
}
__device__ inline float2 unpack2(unsigned int u) {
    __half2 h = *reinterpret_cast<__half2*>(&u);
    return __half22float2(h);
}

// ---- partition src (keys only, ushort payload) ----------------------------
__global__ __launch_bounds__(PTH) void k_part_src(const int* __restrict__ src,
                                                  unsigned short* __restrict__ ps,
                                                  unsigned int* __restrict__ cur,
                                                  int n_edges) {
    __shared__ unsigned int hist[NBKT];
    __shared__ unsigned int base[NBKT];
    const int tid = threadIdx.x;
    const int e0 = blockIdx.x * CHUNK;
    for (int i = tid; i < NBKT; i += PTH) hist[i] = 0;
    __syncthreads();
    unsigned int sv[EPT];
    unsigned int rk[EPT];
#pragma unroll
    for (int k = 0; k < EPT; ++k) {
        int e = e0 + k * PTH + tid;
        if (e < n_edges) {
            unsigned int s = (unsigned int)src[e];
            sv[k] = s;
            rk[k] = atomicAdd(&hist[s >> BSHIFT], 1u);
        } else {
            sv[k] = 0xFFFFFFFFu;
        }
    }
    __syncthreads();
    if (tid < NBKT) base[tid] = atomicAdd(&cur[tid], hist[tid]);
    __syncthreads();
#pragma unroll
    for (int k = 0; k < EPT; ++k) {
        if (sv[k] != 0xFFFFFFFFu) {
            unsigned int b = sv[k] >> BSHIFT;
            ps[b * CAP + base[b] + rk[k]] = (unsigned short)(sv[k] & BMASK);
        }
    }
}

// ---- partition dst with packed (src,dstlow) payload -----------------------
__global__ __launch_bounds__(PTH) void k_part_dst(const int* __restrict__ src,
                                                  const int* __restrict__ dst,
                                                  unsigned int* __restrict__ pd,
                                                  unsigned int* __restrict__ cur,
                                                  int n_edges) {
    __shared__ unsigned int hist[NBKT];
    __shared__ unsigned int base[NBKT];
    const int tid = threadIdx.x;
    const int e0 = blockIdx.x * CHUNK;
    for (int i = tid; i < NBKT; i += PTH) hist[i] = 0;
    __syncthreads();
    unsigned int wv[EPT];
    unsigned int br[EPT];
#pragma unroll
    for (int k = 0; k < EPT; ++k) {
        int e = e0 + k * PTH + tid;
        if (e < n_edges) {
            unsigned int d = (unsigned int)dst[e];
            unsigned int s = (unsigned int)src[e];
            unsigned int b = d >> BSHIFT;
            wv[k] = (s << BSHIFT) | (d & BMASK);
            unsigned int r = atomicAdd(&hist[b], 1u);
            br[k] = (b << 20) | r;
        } else {
            br[k] = 0xFFFFFFFFu;
        }
    }
    __syncthreads();
    if (tid < NBKT) base[tid] = atomicAdd(&cur[tid], hist[tid]);
    __syncthreads();
#pragma unroll
    for (int k = 0; k < EPT; ++k) {
        if (br[k] != 0xFFFFFFFFu) {
            unsigned int b = br[k] >> 20;
            unsigned int r = br[k] & 0xFFFFFu;
            pd[b * CAP + base[b] + r] = wv[k];
        }
    }
}

// ---- in-place counting sort of one bucket's edges by src-super ------------
__global__ __launch_bounds__(512) void k_reorder(unsigned int* __restrict__ pd,
                                                 const unsigned int* __restrict__ cur) {
    __shared__ unsigned int hist[NSUP];
    __shared__ unsigned int curs[NSUP];
    const int b = blockIdx.x, tid = threadIdx.x;
    if (tid < NSUP) hist[tid] = 0;
    __syncthreads();
    const unsigned int n = cur[b];
    const unsigned int base = (unsigned int)b * CAP;
    unsigned int rv[RPT];
#pragma unroll
    for (int k = 0; k < RPT; ++k) {
        unsigned int i = (unsigned int)k * 512u + (unsigned int)tid;
        rv[k] = 0xFFFFFFFFu;
        if (i < n) {
            rv[k] = pd[base + i];
            atomicAdd(&hist[rv[k] >> 24], 1u);
        }
    }
    __syncthreads();
    if (tid == 0) {
        unsigned int run = 0;
        for (int s = 0; s < NSUP; ++s) { curs[s] = run; run += hist[s]; }
    }
    __syncthreads();
#pragma unroll
    for (int k = 0; k < RPT; ++k) {
        if (rv[k] != 0xFFFFFFFFu) {
            unsigned int pos = atomicAdd(&curs[rv[k] >> 24], 1u);
            pd[base + pos] = rv[k];
        }
    }
}

// ---- out-degree histogram per src bucket -> onorm -------------------------
__global__ __launch_bounds__(512) void k_deg_src(const unsigned short* __restrict__ ps,
                                                 const unsigned int* __restrict__ cur,
                                                 float* __restrict__ onorm, int n_nodes) {
    __shared__ unsigned int cnt[1 << BSHIFT];
    const int b = blockIdx.x, tid = threadIdx.x;
    for (int i = tid; i < (1 << BSHIFT); i += 512) cnt[i] = 0;
    __syncthreads();
    const unsigned int n = cur[b];
    const unsigned int base = (unsigned int)b * CAP;
    const unsigned int nfull = n & ~4095u;
    for (unsigned int i0 = 0; i0 < nfull; i0 += 4096) {
        uint4 p = *(const uint4*)(ps + base + i0 + (unsigned int)tid * 8u);
        unsigned int w[4] = {p.x, p.y, p.z, p.w};
#pragma unroll
        for (int k = 0; k < 4; ++k) {
            atomicAdd(&cnt[w[k] & 0xFFFFu], 1u);
            atomicAdd(&cnt[w[k] >> 16], 1u);
        }
    }
    for (unsigned int i = nfull + tid; i < n; i += 512) atomicAdd(&cnt[ps[base + i]], 1u);
    __syncthreads();
    for (int r = tid; r < (1 << BSHIFT); r += 512) {
        int node = (b << BSHIFT) + r;
        if (node < n_nodes) onorm[node] = rsqrtf(fmaxf((float)cnt[r], 1.0f));
    }
}

// ---- y1 = fp16( (feat @ W1) * onorm )  (10 -> 8) --------------------------
__global__ void k_node1(const float* __restrict__ feat, const float* __restrict__ W1,
                        const float* __restrict__ onorm, uint4* __restrict__ y1,
                        int n_nodes) {
    int i = blockIdx.x * blockDim.x + threadIdx.x;
    if (i >= n_nodes) return;
    float on = onorm[i];
    const float* fr = feat + (size_t)i * 10;
    float f[10];
#pragma unroll
    for (int k = 0; k < 10; ++k) f[k] = fr[k];
    float acc[8];
#pragma unroll
    for (int j = 0; j < 8; ++j) acc[j] = 0.0f;
#pragma unroll
    for (int k = 0; k < 10; ++k)
#pragma unroll
        for (int j = 0; j < 8; ++j) acc[j] = fmaf(f[k], W1[k * 8 + j], acc[j]);
    uint4 o;
    o.x = pack2(acc[0] * on, acc[1] * on);
    o.y = pack2(acc[2] * on, acc[3] * on);
    o.z = pack2(acc[4] * on, acc[5] * on);
    o.w = pack2(acc[6] * on, acc[7] * on);
    y1[i] = o;
}

// ---- layer-1 aggregation, swizzled LDS, counts in-degree ------------------
// acc index for (d,j): d*8 + ((j + (d>>2)) & 7)  -> bank uses d bits 0..4 -> 32 banks
__global__ __launch_bounds__(512) void k_agg1(const unsigned int* __restrict__ pd,
                                              const unsigned int* __restrict__ cur,
                                              const uint4* __restrict__ y,
                                              const float* __restrict__ bias,
                                              float* __restrict__ h,
                                              float* __restrict__ innorm, int n_nodes) {
    __shared__ float acc[(1 << BSHIFT) * 8];
    __shared__ unsigned int cnt[1 << BSHIFT];
    const int b = blockIdx.x, tid = threadIdx.x;
    for (int i = tid; i < (1 << BSHIFT) * 8; i += 512) acc[i] = 0.0f;
    for (int i = tid; i < (1 << BSHIFT); i += 512) cnt[i] = 0;
    __syncthreads();
    const unsigned int n = cur[b];
    const unsigned int base = (unsigned int)b * CAP;
    const unsigned int nfull = n & ~4095u;
    for (unsigned int i0 = 0; i0 < nfull; i0 += 4096) {
        const unsigned int s0 = base + i0 + (unsigned int)tid * 8u;
        uint4 p0 = *(const uint4*)(pd + s0);
        uint4 p1 = *(const uint4*)(pd + s0 + 4);
        unsigned int w[8] = {p0.x, p0.y, p0.z, p0.w, p1.x, p1.y, p1.z, p1.w};
        uint4 v[8];
#pragma unroll
        for (int k = 0; k < 8; ++k) v[k] = y[w[k] >> BSHIFT];
#pragma unroll
        for (int k = 0; k < 8; ++k) {
            unsigned int d = w[k] & BMASK;
            unsigned int rot = (d >> 2) & 7u;
            float* ac = acc + d * 8;
            float2 f0 = unpack2(v[k].x);
            float2 f1 = unpack2(v[k].y);
            float2 f2 = unpack2(v[k].z);
            float2 f3 = unpack2(v[k].w);
            atomicAdd(&cnt[d], 1u);
            atomicAdd(&ac[(0 + rot) & 7], f0.x);
            atomicAdd(&ac[(1 + rot) & 7], f0.y);
            atomicAdd(&ac[(2 + rot) & 7], f1.x);
            atomicAdd(&ac[(3 + rot) & 7], f1.y);
            atomicAdd(&ac[(4 + rot) & 7], f2.x);
            atomicAdd(&ac[(5 + rot) & 7], f2.y);
            atomicAdd(&ac[(6 + rot) & 7], f3.x);
            atomicAdd(&ac[(7 + rot) & 7], f3.y);
        }
    }
    for (unsigned int i = nfull + tid; i < n; i += 512) {
        unsigned int w = pd[base + i];
        unsigned int d = w & BMASK;
        unsigned int rot = (d >> 2) & 7u;
        float* ac = acc + d * 8;
        uint4 v = y[w >> BSHIFT];
        float2 f0 = unpack2(v.x);
        float2 f1 = unpack2(v.y);
        float2 f2 = unpack2(v.z);
        float2 f3 = unpack2(v.w);
        atomicAdd(&cnt[d], 1u);
        atomicAdd(&ac[(0 + rot) & 7], f0.x);
        atomicAdd(&ac[(1 + rot) & 7], f0.y);
        atomicAdd(&ac[(2 + rot) & 7], f1.x);
        atomicAdd(&ac[(3 + rot) & 7], f1.y);
        atomicAdd(&ac[(4 + rot) & 7], f2.x);
        atomicAdd(&ac[(5 + rot) & 7], f2.y);
        atomicAdd(&ac[(6 + rot) & 7], f3.x);
        atomicAdd(&ac[(7 + rot) & 7], f3.y);
    }
    __syncthreads();
    for (int r = tid; r < (1 << BSHIFT); r += 512) {
        int node = (b << BSHIFT) + r;
        if (node >= n_nodes) continue;
        unsigned int rot = ((unsigned int)r >> 2) & 7u;
        const float* ac = acc + r * 8;
        float inn = rsqrtf(fmaxf((float)cnt[r], 1.0f));
        innorm[node] = inn;
        float4 o0, o1;
        o0.x = fmaxf(fmaf(ac[(0 + rot) & 7], inn, bias[0]), 0.0f);
        o0.y = fmaxf(fmaf(ac[(1 + rot) & 7], inn, bias[1]), 0.0f);
        o0.z = fmaxf(fmaf(ac[(2 + rot) & 7], inn, bias[2]), 0.0f);
        o0.w = fmaxf(fmaf(ac[(3 + rot) & 7], inn, bias[3]), 0.0f);
        o1.x = fmaxf(fmaf(ac[(4 + rot) & 7], inn, bias[4]), 0.0f);
        o1.y = fmaxf(fmaf(ac[(5 + rot) & 7], inn, bias[5]), 0.0f);
        o1.z = fmaxf(fmaf(ac[(6 + rot) & 7], inn, bias[6]), 0.0f);
        o1.w = fmaxf(fmaf(ac[(7 + rot) & 7], inn, bias[7]), 0.0f);
        ((float4*)(h + (size_t)node * 8))[0] = o0;
        ((float4*)(h + (size_t)node * 8))[1] = o1;
    }
}

// ---- y2 = fp16( (h1 @ W2) * onorm )  (8 -> 4) -----------------------------
__global__ void k_node2(const float* __restrict__ h1, const float* __restrict__ W2,
                        const float* __restrict__ onorm, uint2* __restrict__ y2,
                        int n_nodes) {
    int i = blockIdx.x * blockDim.x + threadIdx.x;
    if (i >= n_nodes) return;
    float on = onorm[i];
    const float4* hr = (const float4*)(h1 + (size_t)i * 8);
    float4 a0 = hr[0];
    float4 a1 = hr[1];
    float hv[8] = {a0.x, a0.y, a0.z, a0.w, a1.x, a1.y, a1.z, a1.w};
    float acc[4] = {0.0f, 0.0f, 0.0f, 0.0f};
#pragma unroll
    for (int k = 0; k < 8; ++k)
#pragma unroll
        for (int j = 0; j < 4; ++j) acc[j] = fmaf(hv[k], W2[k * 4 + j], acc[j]);
    uint2 o;
    o.x = pack2(acc[0] * on, acc[1] * on);
    o.y = pack2(acc[2] * on, acc[3] * on);
    y2[i] = o;
}

// ---- layer-2 aggregation, swizzled LDS, innorm from global ----------------
// acc index for (d,j): d*4 + ((j + (d>>3)) & 3)  -> 32 banks
__global__ __launch_bounds__(512) void k_agg2(const unsigned int* __restrict__ pd,
                                              const unsigned int* __restrict__ cur,
                                              const uint2* __restrict__ y,
                                              const float* __restrict__ bias,
                                              const float* __restrict__ innorm,
                                              float* __restrict__ h, int n_nodes) {
    __shared__ float acc[(1 << BSHIFT) * 4];
    const int b = blockIdx.x, tid = threadIdx.x;
    for (int i = tid; i < (1 << BSHIFT) * 4; i += 512) acc[i] = 0.0f;
    __syncthreads();
    const unsigned int n = cur[b];
    const unsigned int base = (unsigned int)b * CAP;
    const unsigned int nfull = n & ~4095u;
    for (unsigned int i0 = 0; i0 < nfull; i0 += 4096) {
        const unsigned int s0 = base + i0 + (unsigned int)tid * 8u;
        uint4 p0 = *(const uint4*)(pd + s0);
        uint4 p1 = *(const uint4*)(pd + s0 + 4);
        unsigned int w[8] = {p0.x, p0.y, p0.z, p0.w, p1.x, p1.y, p1.z, p1.w};
        uint2 v[8];
#pragma unroll
        for (int k = 0; k < 8; ++k) v[k] = y[w[k] >> BSHIFT];
#pragma unroll
        for (int k = 0; k < 8; ++k) {
            unsigned int d = w[k] & BMASK;
            unsigned int rot = (d >> 3) & 3u;
            float* ac = acc + d * 4;
            float2 f0 = unpack2(v[k].x);
            float2 f1 = unpack2(v[k].y);
            atomicAdd(&ac[(0 + rot) & 3], f0.x);
            atomicAdd(&ac[(1 + rot) & 3], f0.y);
            atomicAdd(&ac[(2 + rot) & 3], f1.x);
            atomicAdd(&ac[(3 + rot) & 3], f1.y);
        }
    }
    for (unsigned int i = nfull + tid; i < n; i += 512) {
        unsigned int w = pd[base + i];
        unsigned int d = w & BMASK;
        unsigned int rot = (d >> 3) & 3u;
        float* ac = acc + d * 4;
        uint2 v = y[w >> BSHIFT];
        float2 f0 = unpack2(v.x);
        float2 f1 = unpack2(v.y);
        atomicAdd(&ac[(0 + rot) & 3], f0.x);
        atomicAdd(&ac[(1 + rot) & 3], f0.y);
        atomicAdd(&ac[(2 + rot) & 3], f1.x);
        atomicAdd(&ac[(3 + rot) & 3], f1.y);
    }
    __syncthreads();
    for (int r = tid; r < (1 << BSHIFT); r += 512) {
        int node = (b << BSHIFT) + r;
        if (node >= n_nodes) continue;
        unsigned int rot = ((unsigned int)r >> 3) & 3u;
        const float* ac = acc + r * 4;
        float inn = innorm[node];
        float4 o;
        o.x = fmaxf(fmaf(ac[(0 + rot) & 3], inn, bias[0]), 0.0f);
        o.y = fmaxf(fmaf(ac[(1 + rot) & 3], inn, bias[1]), 0.0f);
        o.z = fmaxf(fmaf(ac[(2 + rot) & 3], inn, bias[2]), 0.0f);
        o.w = fmaxf(fmaf(ac[(3 + rot) & 3], inn, bias[3]), 0.0f);
        ((float4*)(h + (size_t)node * 4))[0] = o;
    }
}

// ---- per-graph pooling (gid sorted -> wave-segmented reduce) --------------
__global__ void k_pool(const float* __restrict__ h2, const int* __restrict__ gid,
                       float* __restrict__ gsum, float* __restrict__ gcnt, int n_nodes) {
    int i = blockIdx.x * blockDim.x + threadIdx.x;
    int lane = threadIdx.x & 63;
    int g = -1;
    float v0 = 0.f, v1 = 0.f, v2 = 0.f, v3 = 0.f, c = 0.f;
    if (i < n_nodes) {
        float4 a = ((const float4*)(h2 + (size_t)i * 4))[0];
        v0 = a.x; v1 = a.y; v2 = a.z; v3 = a.w;
        c = 1.0f;
        g = gid[i];
    }
#pragma unroll
    for (int s = 1; s < 64; s <<= 1) {
        int go   = __shfl_down(g, s);
        float t0 = __shfl_down(v0, s);
        float t1 = __shfl_down(v1, s);
        float t2 = __shfl_down(v2, s);
        float t3 = __shfl_down(v3, s);
        float tc = __shfl_down(c, s);
        if (lane + s < 64 && go == g) {
            v0 += t0; v1 += t1; v2 += t2; v3 += t3; c += tc;
        }
    }
    int gp = __shfl_up(g, 1);
    bool head = (lane == 0) || (gp != g);
    if (g >= 0 && head) {
        unsafeAtomicAdd(&gsum[g * 4 + 0], v0);
        unsafeAtomicAdd(&gsum[g * 4 + 1], v1);
        unsafeAtomicAdd(&gsum[g * 4 + 2], v2);
        unsafeAtomicAdd(&gsum[g * 4 + 3], v3);
        unsafeAtomicAdd(&gcnt[g], c);
    }
}

__global__ void k_final(const float* __restrict__ gsum, const float* __restrict__ gcnt,
                        const float* __restrict__ Wo, const float* __restrict__ bo,
                        float* __restrict__ out, int n_graphs) {
    int i = blockIdx.x * blockDim.x + threadIdx.x;
    if (i >= n_graphs) return;
    float inv = 1.0f / fmaxf(gcnt[i], 1.0f);
    float z = bo[0];
#pragma unroll
    for (int j = 0; j < 4; ++j) z = fmaf(gsum[i * 4 + j] * inv, Wo[j], z);
    out[i] = 1.0f / (1.0f + expf(-z));
}

extern "C" void kernel_launch(void* const* d_in, const int* in_sizes, int n_in,
                              void* d_out, int out_size, void* d_ws, size_t ws_size,
                              hipStream_t stream) {
    const float* feat = (const float*)d_in[0];
    const int*   src  = (const int*)d_in[1];
    const int*   dst  = (const int*)d_in[2];
    const int*   gid  = (const int*)d_in[3];
    const float* W1   = (const float*)d_in[4];
    const float* b1   = (const float*)d_in[5];
    const float* W2   = (const float*)d_in[6];
    const float* b2   = (const float*)d_in[7];
    const float* Wo   = (const float*)d_in[8];
    const float* bo   = (const float*)d_in[9];
    float* out = (float*)d_out;

    const int n_nodes  = in_sizes[0] / 10;
    const int n_edges  = in_sizes[1];
    const int n_graphs = out_size;
    const int nbk_used = (n_nodes + (1 << BSHIFT) - 1) >> BSHIFT;

    unsigned int* ws32 = (unsigned int*)d_ws;
    const size_t PDW = (size_t)NBKT * CAP;
    const size_t n = (size_t)n_nodes;
    unsigned int*   pd     = ws32;
    unsigned short* ps     = (unsigned short*)ws32;       // aliases pd
    unsigned int*   cs     = ws32 + PDW;
    unsigned int*   cd     = cs + NBKT;
    float*          gsum   = (float*)(cd + NBKT);
    float*          gcnt   = gsum + 4 * (size_t)n_graphs;
    float*          onorm  = gcnt + n_graphs;             // [n]
    float*          innorm = onorm + n;                   // [n]
    unsigned int*   ybuf   = (unsigned int*)(innorm + n); // [4n] dw (y1; y2 aliased)
    float*          hbuf   = (float*)(ybuf + 4 * n);      // [8n] dw (h1; h2 aliases)

    hipMemsetAsync(cs, 0, (2 * NBKT + 5 * (size_t)n_graphs) * sizeof(unsigned int), stream);

    const int nchunk = (n_edges + CHUNK - 1) / CHUNK;
    const int B = 256;

    k_part_src<<<nchunk, PTH, 0, stream>>>(src, ps, cs, n_edges);
    k_deg_src<<<nbk_used, 512, 0, stream>>>(ps, cs, onorm, n_nodes);
    k_part_dst<<<nchunk, PTH, 0, stream>>>(src, dst, pd, cd, n_edges);
    k_reorder<<<nbk_used, 512, 0, stream>>>(pd, cd);
    k_node1<<<(n_nodes + B - 1) / B, B, 0, stream>>>(feat, W1, onorm, (uint4*)ybuf, n_nodes);
    k_agg1<<<nbk_used, 512, 0, stream>>>(pd, cd, (const uint4*)ybuf, b1, hbuf, innorm, n_nodes);
    k_node2<<<(n_nodes + B - 1) / B, B, 0, stream>>>(hbuf, W2, onorm, (uint2*)ybuf, n_nodes);
    k_agg2<<<nbk_used, 512, 0, stream>>>(pd, cd, (const uint2*)ybuf, b2, innorm, hbuf, n_nodes);
    k_pool<<<(n_nodes + B - 1) / B, B, 0, stream>>>(hbuf, gid, gsum, gcnt, n_nodes);
    k_final<<<(n_graphs + B - 1) / B, B, 0, stream>>>(gsum, gcnt, Wo, bo, out, n_graphs);
}

// Round 6
// 1058.877 us; speedup vs baseline: 1.5276x; 1.5110x over previous
//
#include <hip/hip_runtime.h>
#include <hip/hip_fp16.h>
#include <math.h>

// ---------------------------------------------------------------------------
// R6: atomic-free aggregation. R2-R5 proved the wall is LDS-atomic issue rate
// (~3 cyc/lane-op: 9/edge -> 686us, 4/edge -> 312us, invariant to banks/ILP/
// locality). Fix: counting-sort each dst-bucket by dst_low (k_sort_dst, only
// 2 lane-atomics/edge), then one-thread-per-dst register summation of the
// contiguous run. node2 fused into agg1 epilogue; pool fused into agg2.
//
// ws layout (dwords):
//   pd     [NBKT*CAP]
//   cs     [NBKT]  cd [NBKT]  gsum [4G]  gcnt [G]   (zeroed via memset)
//   onorm  [n]
//   starts [NBKT*1024]   per-bucket exclusive dst histogram offsets
//   y1     [4n]          fp16 half8 per node
//   y2     [2n]          fp16 half4 per node
// ---------------------------------------------------------------------------

#define BSHIFT 10
#define BMASK  1023u
#define NBKT   1024
#define CAP    17408u
#define SRT    ((CAP + 511) / 512)   // 34 edges/thread in sort
#define EPT    32
#define PTH    1024
#define CHUNK  (PTH * EPT)

__device__ inline unsigned int pack2(float a, float b) {
    __half2 h = __floats2half2_rn(a, b);
    return *reinterpret_cast<unsigned int*>(&h);
}
__device__ inline float2 unpack2(unsigned int u) {
    __half2 h = *reinterpret_cast<__half2*>(&u);
    return __half22float2(h);
}

// ---- partition src (keys only, ushort payload) ----------------------------
__global__ __launch_bounds__(PTH) void k_part_src(const int* __restrict__ src,
                                                  unsigned short* __restrict__ ps,
                                                  unsigned int* __restrict__ cur,
                                                  int n_edges) {
    __shared__ unsigned int hist[NBKT];
    __shared__ unsigned int base[NBKT];
    const int tid = threadIdx.x;
    const int e0 = blockIdx.x * CHUNK;
    for (int i = tid; i < NBKT; i += PTH) hist[i] = 0;
    __syncthreads();
    unsigned int sv[EPT];
    unsigned int rk[EPT];
#pragma unroll
    for (int k = 0; k < EPT; ++k) {
        int e = e0 + k * PTH + tid;
        if (e < n_edges) {
            unsigned int s = (unsigned int)src[e];
            sv[k] = s;
            rk[k] = atomicAdd(&hist[s >> BSHIFT], 1u);
        } else {
            sv[k] = 0xFFFFFFFFu;
        }
    }
    __syncthreads();
    if (tid < NBKT) base[tid] = atomicAdd(&cur[tid], hist[tid]);
    __syncthreads();
#pragma unroll
    for (int k = 0; k < EPT; ++k) {
        if (sv[k] != 0xFFFFFFFFu) {
            unsigned int b = sv[k] >> BSHIFT;
            ps[b * CAP + base[b] + rk[k]] = (unsigned short)(sv[k] & BMASK);
        }
    }
}

// ---- partition dst with packed (src,dstlow) payload -----------------------
__global__ __launch_bounds__(PTH) void k_part_dst(const int* __restrict__ src,
                                                  const int* __restrict__ dst,
                                                  unsigned int* __restrict__ pd,
                                                  unsigned int* __restrict__ cur,
                                                  int n_edges) {
    __shared__ unsigned int hist[NBKT];
    __shared__ unsigned int base[NBKT];
    const int tid = threadIdx.x;
    const int e0 = blockIdx.x * CHUNK;
    for (int i = tid; i < NBKT; i += PTH) hist[i] = 0;
    __syncthreads();
    unsigned int wv[EPT];
    unsigned int br[EPT];
#pragma unroll
    for (int k = 0; k < EPT; ++k) {
        int e = e0 + k * PTH + tid;
        if (e < n_edges) {
            unsigned int d = (unsigned int)dst[e];
            unsigned int s = (unsigned int)src[e];
            unsigned int b = d >> BSHIFT;
            wv[k] = (s << BSHIFT) | (d & BMASK);
            unsigned int r = atomicAdd(&hist[b], 1u);
            br[k] = (b << 20) | r;
        } else {
            br[k] = 0xFFFFFFFFu;
        }
    }
    __syncthreads();
    if (tid < NBKT) base[tid] = atomicAdd(&cur[tid], hist[tid]);
    __syncthreads();
#pragma unroll
    for (int k = 0; k < EPT; ++k) {
        if (br[k] != 0xFFFFFFFFu) {
            unsigned int b = br[k] >> 20;
            unsigned int r = br[k] & 0xFFFFFu;
            pd[b * CAP + base[b] + r] = wv[k];
        }
    }
}

// ---- out-degree histogram per src bucket -> onorm -------------------------
__global__ __launch_bounds__(512) void k_deg_src(const unsigned short* __restrict__ ps,
                                                 const unsigned int* __restrict__ cur,
                                                 float* __restrict__ onorm, int n_nodes) {
    __shared__ unsigned int cnt[1 << BSHIFT];
    const int b = blockIdx.x, tid = threadIdx.x;
    for (int i = tid; i < (1 << BSHIFT); i += 512) cnt[i] = 0;
    __syncthreads();
    const unsigned int n = cur[b];
    const unsigned int base = (unsigned int)b * CAP;
    const unsigned int nfull = n & ~4095u;
    for (unsigned int i0 = 0; i0 < nfull; i0 += 4096) {
        uint4 p = *(const uint4*)(ps + base + i0 + (unsigned int)tid * 8u);
        unsigned int w[4] = {p.x, p.y, p.z, p.w};
#pragma unroll
        for (int k = 0; k < 4; ++k) {
            atomicAdd(&cnt[w[k] & 0xFFFFu], 1u);
            atomicAdd(&cnt[w[k] >> 16], 1u);
        }
    }
    for (unsigned int i = nfull + tid; i < n; i += 512) atomicAdd(&cnt[ps[base + i]], 1u);
    __syncthreads();
    for (int r = tid; r < (1 << BSHIFT); r += 512) {
        int node = (b << BSHIFT) + r;
        if (node < n_nodes) onorm[node] = rsqrtf(fmaxf((float)cnt[r], 1.0f));
    }
}

// ---- counting sort of one bucket's edges by dst_low; emit run offsets -----
__global__ __launch_bounds__(512) void k_sort_dst(unsigned int* __restrict__ pd,
                                                  const unsigned int* __restrict__ cur,
                                                  unsigned int* __restrict__ starts) {
    __shared__ unsigned int sA[1024];
    __shared__ unsigned int sB[1024];
    __shared__ unsigned int curs[1024];
    const int b = blockIdx.x, tid = threadIdx.x;
    for (int i = tid; i < 1024; i += 512) sA[i] = 0;
    __syncthreads();
    const unsigned int n = cur[b];
    const unsigned int base = (unsigned int)b * CAP;
    unsigned int rv[SRT];
#pragma unroll
    for (int k = 0; k < SRT; ++k) {
        unsigned int i = (unsigned int)k * 512u + (unsigned int)tid;
        rv[k] = 0xFFFFFFFFu;
        if (i < n) {
            rv[k] = pd[base + i];
            atomicAdd(&sA[rv[k] & BMASK], 1u);
        }
    }
    __syncthreads();
    // inclusive Hillis-Steele scan over 1024 counts (ping-pong sA<->sB)
    unsigned int* pin = sA;
    unsigned int* pout = sB;
    for (int off = 1; off < 1024; off <<= 1) {
        for (int r = tid; r < 1024; r += 512) {
            unsigned int v = pin[r];
            if (r >= off) v += pin[r - off];
            pout[r] = v;
        }
        __syncthreads();
        unsigned int* t = pin; pin = pout; pout = t;
    }
    // exclusive offsets -> curs + global starts
    for (int r = tid; r < 1024; r += 512) {
        unsigned int st = (r == 0) ? 0u : pin[r - 1];
        curs[r] = st;
        starts[(size_t)b * 1024 + r] = st;
    }
    __syncthreads();
#pragma unroll
    for (int k = 0; k < SRT; ++k) {
        if (rv[k] != 0xFFFFFFFFu) {
            unsigned int pos = atomicAdd(&curs[rv[k] & BMASK], 1u);
            pd[base + pos] = rv[k];
        }
    }
}

// ---- y1 = fp16( (feat @ W1) * onorm )  (10 -> 8) --------------------------
__global__ void k_node1(const float* __restrict__ feat, const float* __restrict__ W1,
                        const float* __restrict__ onorm, uint4* __restrict__ y1,
                        int n_nodes) {
    int i = blockIdx.x * blockDim.x + threadIdx.x;
    if (i >= n_nodes) return;
    float on = onorm[i];
    const float* fr = feat + (size_t)i * 10;
    float f[10];
#pragma unroll
    for (int k = 0; k < 10; ++k) f[k] = fr[k];
    float acc[8];
#pragma unroll
    for (int j = 0; j < 8; ++j) acc[j] = 0.0f;
#pragma unroll
    for (int k = 0; k < 10; ++k)
#pragma unroll
        for (int j = 0; j < 8; ++j) acc[j] = fmaf(f[k], W1[k * 8 + j], acc[j]);
    uint4 o;
    o.x = pack2(acc[0] * on, acc[1] * on);
    o.y = pack2(acc[2] * on, acc[3] * on);
    o.z = pack2(acc[4] * on, acc[5] * on);
    o.w = pack2(acc[6] * on, acc[7] * on);
    y1[i] = o;
}

// ---- layer1 agg (thread-per-dst, atomic-free) + fused node2 ---------------
// h1 = relu(inn*sum + b1) in regs; y2 = fp16( (h1 @ W2) * onorm )
__global__ __launch_bounds__(1024) void k_agg1(const unsigned int* __restrict__ pd,
                                               const unsigned int* __restrict__ cur,
                                               const unsigned int* __restrict__ starts,
                                               const uint4* __restrict__ y,
                                               const float* __restrict__ b1,
                                               const float* __restrict__ W2,
                                               const float* __restrict__ onorm,
                                               uint2* __restrict__ y2, int n_nodes) {
    const int b = blockIdx.x;
    const int r = threadIdx.x;
    const int node = (b << BSHIFT) + r;
    if (node >= n_nodes) return;
    const unsigned int n = cur[b];
    const unsigned int base = (unsigned int)b * CAP;
    const unsigned int* st = starts + (size_t)b * 1024;
    unsigned int s = st[r];
    unsigned int e = (r == 1023) ? n : st[r + 1];
    float acc[8];
#pragma unroll
    for (int j = 0; j < 8; ++j) acc[j] = 0.0f;
    unsigned int i = s;
    for (; i + 4 <= e; i += 4) {
        unsigned int w0 = pd[base + i + 0];
        unsigned int w1 = pd[base + i + 1];
        unsigned int w2 = pd[base + i + 2];
        unsigned int w3 = pd[base + i + 3];
        uint4 v0 = y[w0 >> BSHIFT];
        uint4 v1 = y[w1 >> BSHIFT];
        uint4 v2 = y[w2 >> BSHIFT];
        uint4 v3 = y[w3 >> BSHIFT];
        uint4 vv[4] = {v0, v1, v2, v3};
#pragma unroll
        for (int k = 0; k < 4; ++k) {
            float2 f0 = unpack2(vv[k].x);
            float2 f1 = unpack2(vv[k].y);
            float2 f2 = unpack2(vv[k].z);
            float2 f3 = unpack2(vv[k].w);
            acc[0] += f0.x; acc[1] += f0.y; acc[2] += f1.x; acc[3] += f1.y;
            acc[4] += f2.x; acc[5] += f2.y; acc[6] += f3.x; acc[7] += f3.y;
        }
    }
    for (; i < e; ++i) {
        unsigned int w = pd[base + i];
        uint4 v = y[w >> BSHIFT];
        float2 f0 = unpack2(v.x);
        float2 f1 = unpack2(v.y);
        float2 f2 = unpack2(v.z);
        float2 f3 = unpack2(v.w);
        acc[0] += f0.x; acc[1] += f0.y; acc[2] += f1.x; acc[3] += f1.y;
        acc[4] += f2.x; acc[5] += f2.y; acc[6] += f3.x; acc[7] += f3.y;
    }
    float inn = rsqrtf(fmaxf((float)(e - s), 1.0f));
    float h[8];
#pragma unroll
    for (int j = 0; j < 8; ++j) h[j] = fmaxf(fmaf(acc[j], inn, b1[j]), 0.0f);
    float z[4] = {0.0f, 0.0f, 0.0f, 0.0f};
#pragma unroll
    for (int k = 0; k < 8; ++k)
#pragma unroll
        for (int j = 0; j < 4; ++j) z[j] = fmaf(h[k], W2[k * 4 + j], z[j]);
    float on = onorm[node];
    uint2 o;
    o.x = pack2(z[0] * on, z[1] * on);
    o.y = pack2(z[2] * on, z[3] * on);
    y2[node] = o;
}

// ---- layer2 agg (thread-per-dst, atomic-free) + fused graph pooling -------
__global__ __launch_bounds__(1024) void k_agg2(const unsigned int* __restrict__ pd,
                                               const unsigned int* __restrict__ cur,
                                               const unsigned int* __restrict__ starts,
                                               const uint2* __restrict__ y,
                                               const float* __restrict__ b2,
                                               const int* __restrict__ gid,
                                               float* __restrict__ gsum,
                                               float* __restrict__ gcnt, int n_nodes) {
    const int b = blockIdx.x;
    const int r = threadIdx.x;
    const int node = (b << BSHIFT) + r;
    const int lane = threadIdx.x & 63;
    int g = -1;
    float v0 = 0.f, v1 = 0.f, v2 = 0.f, v3 = 0.f, c = 0.f;
    if (node < n_nodes) {
        const unsigned int n = cur[b];
        const unsigned int base = (unsigned int)b * CAP;
        const unsigned int* st = starts + (size_t)b * 1024;
        unsigned int s = st[r];
        unsigned int e = (r == 1023) ? n : st[r + 1];
        float acc[4] = {0.0f, 0.0f, 0.0f, 0.0f};
        unsigned int i = s;
        for (; i + 4 <= e; i += 4) {
            unsigned int w0 = pd[base + i + 0];
            unsigned int w1 = pd[base + i + 1];
            unsigned int w2 = pd[base + i + 2];
            unsigned int w3 = pd[base + i + 3];
            uint2 q0 = y[w0 >> BSHIFT];
            uint2 q1 = y[w1 >> BSHIFT];
            uint2 q2 = y[w2 >> BSHIFT];
            uint2 q3 = y[w3 >> BSHIFT];
            uint2 qq[4] = {q0, q1, q2, q3};
#pragma unroll
            for (int k = 0; k < 4; ++k) {
                float2 f0 = unpack2(qq[k].x);
                float2 f1 = unpack2(qq[k].y);
                acc[0] += f0.x; acc[1] += f0.y; acc[2] += f1.x; acc[3] += f1.y;
            }
        }
        for (; i < e; ++i) {
            unsigned int w = pd[base + i];
            uint2 q = y[w >> BSHIFT];
            float2 f0 = unpack2(q.x);
            float2 f1 = unpack2(q.y);
            acc[0] += f0.x; acc[1] += f0.y; acc[2] += f1.x; acc[3] += f1.y;
        }
        float inn = rsqrtf(fmaxf((float)(e - s), 1.0f));
        v0 = fmaxf(fmaf(acc[0], inn, b2[0]), 0.0f);
        v1 = fmaxf(fmaf(acc[1], inn, b2[1]), 0.0f);
        v2 = fmaxf(fmaf(acc[2], inn, b2[2]), 0.0f);
        v3 = fmaxf(fmaf(acc[3], inn, b2[3]), 0.0f);
        c = 1.0f;
        g = gid[node];
    }
    // wave-segmented suffix reduce (gid sorted; nodes consecutive per lane)
#pragma unroll
    for (int sft = 1; sft < 64; sft <<= 1) {
        int go   = __shfl_down(g, sft);
        float t0 = __shfl_down(v0, sft);
        float t1 = __shfl_down(v1, sft);
        float t2 = __shfl_down(v2, sft);
        float t3 = __shfl_down(v3, sft);
        float tc = __shfl_down(c, sft);
        if (lane + sft < 64 && go == g) {
            v0 += t0; v1 += t1; v2 += t2; v3 += t3; c += tc;
        }
    }
    int gp = __shfl_up(g, 1);
    bool head = (lane == 0) || (gp != g);
    if (g >= 0 && head) {
        unsafeAtomicAdd(&gsum[g * 4 + 0], v0);
        unsafeAtomicAdd(&gsum[g * 4 + 1], v1);
        unsafeAtomicAdd(&gsum[g * 4 + 2], v2);
        unsafeAtomicAdd(&gsum[g * 4 + 3], v3);
        unsafeAtomicAdd(&gcnt[g], c);
    }
}

__global__ void k_final(const float* __restrict__ gsum, const float* __restrict__ gcnt,
                        const float* __restrict__ Wo, const float* __restrict__ bo,
                        float* __restrict__ out, int n_graphs) {
    int i = blockIdx.x * blockDim.x + threadIdx.x;
    if (i >= n_graphs) return;
    float inv = 1.0f / fmaxf(gcnt[i], 1.0f);
    float z = bo[0];
#pragma unroll
    for (int j = 0; j < 4; ++j) z = fmaf(gsum[i * 4 + j] * inv, Wo[j], z);
    out[i] = 1.0f / (1.0f + expf(-z));
}

extern "C" void kernel_launch(void* const* d_in, const int* in_sizes, int n_in,
                              void* d_out, int out_size, void* d_ws, size_t ws_size,
                              hipStream_t stream) {
    const float* feat = (const float*)d_in[0];
    const int*   src  = (const int*)d_in[1];
    const int*   dst  = (const int*)d_in[2];
    const int*   gid  = (const int*)d_in[3];
    const float* W1   = (const float*)d_in[4];
    const float* b1   = (const float*)d_in[5];
    const float* W2   = (const float*)d_in[6];
    const float* b2   = (const float*)d_in[7];
    const float* Wo   = (const float*)d_in[8];
    const float* bo   = (const float*)d_in[9];
    float* out = (float*)d_out;

    const int n_nodes  = in_sizes[0] / 10;
    const int n_edges  = in_sizes[1];
    const int n_graphs = out_size;
    const int nbk_used = (n_nodes + (1 << BSHIFT) - 1) >> BSHIFT;

    unsigned int* ws32 = (unsigned int*)d_ws;
    const size_t PDW = (size_t)NBKT * CAP;
    const size_t n = (size_t)n_nodes;
    unsigned int*   pd     = ws32;
    unsigned short* ps     = (unsigned short*)ws32;        // aliases pd (time-muxed)
    unsigned int*   cs     = ws32 + PDW;
    unsigned int*   cd     = cs + NBKT;
    float*          gsum   = (float*)(cd + NBKT);
    float*          gcnt   = gsum + 4 * (size_t)n_graphs;
    float*          onorm  = gcnt + n_graphs;              // [n]
    unsigned int*   starts = (unsigned int*)(onorm + n);   // [NBKT*1024]
    unsigned int*   y1     = starts + (size_t)NBKT * 1024; // [4n] dw, 16B aligned
    unsigned int*   y2     = y1 + 4 * n;                   // [2n] dw

    hipMemsetAsync(cs, 0, (2 * NBKT + 5 * (size_t)n_graphs) * sizeof(unsigned int), stream);

    const int nchunk = (n_edges + CHUNK - 1) / CHUNK;
    const int B = 256;

    k_part_src<<<nchunk, PTH, 0, stream>>>(src, ps, cs, n_edges);
    k_deg_src<<<nbk_used, 512, 0, stream>>>(ps, cs, onorm, n_nodes);
    k_part_dst<<<nchunk, PTH, 0, stream>>>(src, dst, pd, cd, n_edges);
    k_sort_dst<<<nbk_used, 512, 0, stream>>>(pd, cd, starts);
    k_node1<<<(n_nodes + B - 1) / B, B, 0, stream>>>(feat, W1, onorm, (uint4*)y1, n_nodes);
    k_agg1<<<nbk_used, 1024, 0, stream>>>(pd, cd, starts, (const uint4*)y1, b1, W2, onorm,
                                          (uint2*)y2, n_nodes);
    k_agg2<<<nbk_used, 1024, 0, stream>>>(pd, cd, starts, (const uint2*)y2, b2, gid,
                                          gsum, gcnt, n_nodes);
    k_final<<<(n_graphs + B - 1) / B, B, 0, stream>>>(gsum, gcnt, Wo, bo, out, n_graphs);
}

// Round 8
// 927.631 us; speedup vs baseline: 1.7437x; 1.1415x over previous
//
#include <hip/hip_runtime.h>
#include <hip/hip_fp16.h>
#include <math.h>

// ---------------------------------------------------------------------------
// R7b: fp8(e4m3, HW cvt) node features; compile fix -- cvt_pk_f32_fp8's hi
// selector must be a literal constant -> template<bool HI>.
// R6 made aggregation atomic-free and exposed the true wall: random 64B-line
// fetches (997 MB for agg1 = 16M gathers x 64B, y1=16MB >> 4MB/XCD L2).
// fp8 halves row bytes again: y1 = 8 MB (~2x L2), y2 = 4 MB (~L2-resident).
//
// ws layout (dwords):
//   pd     [NBKT*CAP]
//   cs     [NBKT]  cd [NBKT]  gsum [4G]  gcnt [G]   (zeroed via memset)
//   onorm  [n]
//   starts [NBKT*1024]
//   y1     [2n]   fp8x8 per node (8 B)
//   y2     [n]    fp8x4 per node (4 B)
// ---------------------------------------------------------------------------

#define BSHIFT 10
#define BMASK  1023u
#define NBKT   1024
#define CAP    17408u
#define SRT    ((CAP + 511) / 512)
#define EPT    32
#define PTH    1024
#define CHUNK  (PTH * EPT)

typedef float v2f __attribute__((ext_vector_type(2)));

template <bool HI>
__device__ inline v2f up8(unsigned int w) {
    return __builtin_amdgcn_cvt_pk_f32_fp8((int)w, HI);
}
__device__ inline unsigned int pk4(float a, float b, float c, float d) {
    int r = __builtin_amdgcn_cvt_pk_fp8_f32(a, b, 0, false);
    r = __builtin_amdgcn_cvt_pk_fp8_f32(c, d, r, true);
    return (unsigned int)r;
}

// ---- partition src (keys only, ushort payload) ----------------------------
__global__ __launch_bounds__(PTH) void k_part_src(const int* __restrict__ src,
                                                  unsigned short* __restrict__ ps,
                                                  unsigned int* __restrict__ cur,
                                                  int n_edges) {
    __shared__ unsigned int hist[NBKT];
    __shared__ unsigned int base[NBKT];
    const int tid = threadIdx.x;
    const int e0 = blockIdx.x * CHUNK;
    for (int i = tid; i < NBKT; i += PTH) hist[i] = 0;
    __syncthreads();
    unsigned int sv[EPT];
    unsigned int rk[EPT];
#pragma unroll
    for (int k = 0; k < EPT; ++k) {
        int e = e0 + k * PTH + tid;
        if (e < n_edges) {
            unsigned int s = (unsigned int)src[e];
            sv[k] = s;
            rk[k] = atomicAdd(&hist[s >> BSHIFT], 1u);
        } else {
            sv[k] = 0xFFFFFFFFu;
        }
    }
    __syncthreads();
    if (tid < NBKT) base[tid] = atomicAdd(&cur[tid], hist[tid]);
    __syncthreads();
#pragma unroll
    for (int k = 0; k < EPT; ++k) {
        if (sv[k] != 0xFFFFFFFFu) {
            unsigned int b = sv[k] >> BSHIFT;
            ps[b * CAP + base[b] + rk[k]] = (unsigned short)(sv[k] & BMASK);
        }
    }
}

// ---- partition dst with packed (src,dstlow) payload -----------------------
__global__ __launch_bounds__(PTH) void k_part_dst(const int* __restrict__ src,
                                                  const int* __restrict__ dst,
                                                  unsigned int* __restrict__ pd,
                                                  unsigned int* __restrict__ cur,
                                                  int n_edges) {
    __shared__ unsigned int hist[NBKT];
    __shared__ unsigned int base[NBKT];
    const int tid = threadIdx.x;
    const int e0 = blockIdx.x * CHUNK;
    for (int i = tid; i < NBKT; i += PTH) hist[i] = 0;
    __syncthreads();
    unsigned int wv[EPT];
    unsigned int br[EPT];
#pragma unroll
    for (int k = 0; k < EPT; ++k) {
        int e = e0 + k * PTH + tid;
        if (e < n_edges) {
            unsigned int d = (unsigned int)dst[e];
            unsigned int s = (unsigned int)src[e];
            unsigned int b = d >> BSHIFT;
            wv[k] = (s << BSHIFT) | (d & BMASK);
            unsigned int r = atomicAdd(&hist[b], 1u);
            br[k] = (b << 20) | r;
        } else {
            br[k] = 0xFFFFFFFFu;
        }
    }
    __syncthreads();
    if (tid < NBKT) base[tid] = atomicAdd(&cur[tid], hist[tid]);
    __syncthreads();
#pragma unroll
    for (int k = 0; k < EPT; ++k) {
        if (br[k] != 0xFFFFFFFFu) {
            unsigned int b = br[k] >> 20;
            unsigned int r = br[k] & 0xFFFFFu;
            pd[b * CAP + base[b] + r] = wv[k];
        }
    }
}

// ---- out-degree histogram per src bucket -> onorm -------------------------
__global__ __launch_bounds__(512) void k_deg_src(const unsigned short* __restrict__ ps,
                                                 const unsigned int* __restrict__ cur,
                                                 float* __restrict__ onorm, int n_nodes) {
    __shared__ unsigned int cnt[1 << BSHIFT];
    const int b = blockIdx.x, tid = threadIdx.x;
    for (int i = tid; i < (1 << BSHIFT); i += 512) cnt[i] = 0;
    __syncthreads();
    const unsigned int n = cur[b];
    const unsigned int base = (unsigned int)b * CAP;
    const unsigned int nfull = n & ~4095u;
    for (unsigned int i0 = 0; i0 < nfull; i0 += 4096) {
        uint4 p = *(const uint4*)(ps + base + i0 + (unsigned int)tid * 8u);
        unsigned int w[4] = {p.x, p.y, p.z, p.w};
#pragma unroll
        for (int k = 0; k < 4; ++k) {
            atomicAdd(&cnt[w[k] & 0xFFFFu], 1u);
            atomicAdd(&cnt[w[k] >> 16], 1u);
        }
    }
    for (unsigned int i = nfull + tid; i < n; i += 512) atomicAdd(&cnt[ps[base + i]], 1u);
    __syncthreads();
    for (int r = tid; r < (1 << BSHIFT); r += 512) {
        int node = (b << BSHIFT) + r;
        if (node < n_nodes) onorm[node] = rsqrtf(fmaxf((float)cnt[r], 1.0f));
    }
}

// ---- counting sort of one bucket's edges by dst_low; emit run offsets -----
__global__ __launch_bounds__(512) void k_sort_dst(unsigned int* __restrict__ pd,
                                                  const unsigned int* __restrict__ cur,
                                                  unsigned int* __restrict__ starts) {
    __shared__ unsigned int sA[1024];
    __shared__ unsigned int sB[1024];
    __shared__ unsigned int curs[1024];
    const int b = blockIdx.x, tid = threadIdx.x;
    for (int i = tid; i < 1024; i += 512) sA[i] = 0;
    __syncthreads();
    const unsigned int n = cur[b];
    const unsigned int base = (unsigned int)b * CAP;
    unsigned int rv[SRT];
#pragma unroll
    for (int k = 0; k < SRT; ++k) {
        unsigned int i = (unsigned int)k * 512u + (unsigned int)tid;
        rv[k] = 0xFFFFFFFFu;
        if (i < n) {
            rv[k] = pd[base + i];
            atomicAdd(&sA[rv[k] & BMASK], 1u);
        }
    }
    __syncthreads();
    unsigned int* pin = sA;
    unsigned int* pout = sB;
    for (int off = 1; off < 1024; off <<= 1) {
        for (int r = tid; r < 1024; r += 512) {
            unsigned int v = pin[r];
            if (r >= off) v += pin[r - off];
            pout[r] = v;
        }
        __syncthreads();
        unsigned int* t = pin; pin = pout; pout = t;
    }
    for (int r = tid; r < 1024; r += 512) {
        unsigned int st = (r == 0) ? 0u : pin[r - 1];
        curs[r] = st;
        starts[(size_t)b * 1024 + r] = st;
    }
    __syncthreads();
#pragma unroll
    for (int k = 0; k < SRT; ++k) {
        if (rv[k] != 0xFFFFFFFFu) {
            unsigned int pos = atomicAdd(&curs[rv[k] & BMASK], 1u);
            pd[base + pos] = rv[k];
        }
    }
}

// ---- y1 = fp8( (feat @ W1) * onorm )  (10 -> 8) ---------------------------
__global__ void k_node1(const float* __restrict__ feat, const float* __restrict__ W1,
                        const float* __restrict__ onorm, uint2* __restrict__ y1,
                        int n_nodes) {
    int i = blockIdx.x * blockDim.x + threadIdx.x;
    if (i >= n_nodes) return;
    float on = onorm[i];
    const float* fr = feat + (size_t)i * 10;
    float f[10];
#pragma unroll
    for (int k = 0; k < 10; ++k) f[k] = fr[k];
    float acc[8];
#pragma unroll
    for (int j = 0; j < 8; ++j) acc[j] = 0.0f;
#pragma unroll
    for (int k = 0; k < 10; ++k)
#pragma unroll
        for (int j = 0; j < 8; ++j) acc[j] = fmaf(f[k], W1[k * 8 + j], acc[j]);
    uint2 o;
    o.x = pk4(acc[0] * on, acc[1] * on, acc[2] * on, acc[3] * on);
    o.y = pk4(acc[4] * on, acc[5] * on, acc[6] * on, acc[7] * on);
    y1[i] = o;
}

// ---- layer1 agg (thread-per-dst, atomic-free) + fused node2 ---------------
__global__ __launch_bounds__(1024) void k_agg1(const unsigned int* __restrict__ pd,
                                               const unsigned int* __restrict__ cur,
                                               const unsigned int* __restrict__ starts,
                                               const uint2* __restrict__ y,
                                               const float* __restrict__ b1,
                                               const float* __restrict__ W2,
                                               const float* __restrict__ onorm,
                                               unsigned int* __restrict__ y2, int n_nodes) {
    const int b = blockIdx.x;
    const int r = threadIdx.x;
    const int node = (b << BSHIFT) + r;
    if (node >= n_nodes) return;
    const unsigned int n = cur[b];
    const unsigned int base = (unsigned int)b * CAP;
    const unsigned int* st = starts + (size_t)b * 1024;
    unsigned int s = st[r];
    unsigned int e = (r == 1023) ? n : st[r + 1];
    float acc[8];
#pragma unroll
    for (int j = 0; j < 8; ++j) acc[j] = 0.0f;
    unsigned int i = s;
    for (; i + 4 <= e; i += 4) {
        unsigned int w0 = pd[base + i + 0];
        unsigned int w1 = pd[base + i + 1];
        unsigned int w2 = pd[base + i + 2];
        unsigned int w3 = pd[base + i + 3];
        uint2 v0 = y[w0 >> BSHIFT];
        uint2 v1 = y[w1 >> BSHIFT];
        uint2 v2 = y[w2 >> BSHIFT];
        uint2 v3 = y[w3 >> BSHIFT];
        uint2 vv[4] = {v0, v1, v2, v3};
#pragma unroll
        for (int k = 0; k < 4; ++k) {
            v2f f0 = up8<false>(vv[k].x);
            v2f f1 = up8<true>(vv[k].x);
            v2f f2 = up8<false>(vv[k].y);
            v2f f3 = up8<true>(vv[k].y);
            acc[0] += f0.x; acc[1] += f0.y; acc[2] += f1.x; acc[3] += f1.y;
            acc[4] += f2.x; acc[5] += f2.y; acc[6] += f3.x; acc[7] += f3.y;
        }
    }
    for (; i < e; ++i) {
        unsigned int w = pd[base + i];
        uint2 v = y[w >> BSHIFT];
        v2f f0 = up8<false>(v.x);
        v2f f1 = up8<true>(v.x);
        v2f f2 = up8<false>(v.y);
        v2f f3 = up8<true>(v.y);
        acc[0] += f0.x; acc[1] += f0.y; acc[2] += f1.x; acc[3] += f1.y;
        acc[4] += f2.x; acc[5] += f2.y; acc[6] += f3.x; acc[7] += f3.y;
    }
    float inn = rsqrtf(fmaxf((float)(e - s), 1.0f));
    float h[8];
#pragma unroll
    for (int j = 0; j < 8; ++j) h[j] = fmaxf(fmaf(acc[j], inn, b1[j]), 0.0f);
    float z[4] = {0.0f, 0.0f, 0.0f, 0.0f};
#pragma unroll
    for (int k = 0; k < 8; ++k)
#pragma unroll
        for (int j = 0; j < 4; ++j) z[j] = fmaf(h[k], W2[k * 4 + j], z[j]);
    float on = onorm[node];
    y2[node] = pk4(z[0] * on, z[1] * on, z[2] * on, z[3] * on);
}

// ---- layer2 agg (thread-per-dst, atomic-free) + fused graph pooling -------
__global__ __launch_bounds__(1024) void k_agg2(const unsigned int* __restrict__ pd,
                                               const unsigned int* __restrict__ cur,
                                               const unsigned int* __restrict__ starts,
                                               const unsigned int* __restrict__ y,
                                               const float* __restrict__ b2,
                                               const int* __restrict__ gid,
                                               float* __restrict__ gsum,
                                               float* __restrict__ gcnt, int n_nodes) {
    const int b = blockIdx.x;
    const int r = threadIdx.x;
    const int node = (b << BSHIFT) + r;
    const int lane = threadIdx.x & 63;
    int g = -1;
    float v0 = 0.f, v1 = 0.f, v2 = 0.f, v3 = 0.f, c = 0.f;
    if (node < n_nodes) {
        const unsigned int n = cur[b];
        const unsigned int base = (unsigned int)b * CAP;
        const unsigned int* st = starts + (size_t)b * 1024;
        unsigned int s = st[r];
        unsigned int e = (r == 1023) ? n : st[r + 1];
        float acc[4] = {0.0f, 0.0f, 0.0f, 0.0f};
        unsigned int i = s;
        for (; i + 4 <= e; i += 4) {
            unsigned int w0 = pd[base + i + 0];
            unsigned int w1 = pd[base + i + 1];
            unsigned int w2 = pd[base + i + 2];
            unsigned int w3 = pd[base + i + 3];
            unsigned int q[4] = {y[w0 >> BSHIFT], y[w1 >> BSHIFT],
                                 y[w2 >> BSHIFT], y[w3 >> BSHIFT]};
#pragma unroll
            for (int k = 0; k < 4; ++k) {
                v2f f0 = up8<false>(q[k]);
                v2f f1 = up8<true>(q[k]);
                acc[0] += f0.x; acc[1] += f0.y; acc[2] += f1.x; acc[3] += f1.y;
            }
        }
        for (; i < e; ++i) {
            unsigned int w = pd[base + i];
            unsigned int q = y[w >> BSHIFT];
            v2f f0 = up8<false>(q);
            v2f f1 = up8<true>(q);
            acc[0] += f0.x; acc[1] += f0.y; acc[2] += f1.x; acc[3] += f1.y;
        }
        float inn = rsqrtf(fmaxf((float)(e - s), 1.0f));
        v0 = fmaxf(fmaf(acc[0], inn, b2[0]), 0.0f);
        v1 = fmaxf(fmaf(acc[1], inn, b2[1]), 0.0f);
        v2 = fmaxf(fmaf(acc[2], inn, b2[2]), 0.0f);
        v3 = fmaxf(fmaf(acc[3], inn, b2[3]), 0.0f);
        c = 1.0f;
        g = gid[node];
    }
#pragma unroll
    for (int sft = 1; sft < 64; sft <<= 1) {
        int go   = __shfl_down(g, sft);
        float t0 = __shfl_down(v0, sft);
        float t1 = __shfl_down(v1, sft);
        float t2 = __shfl_down(v2, sft);
        float t3 = __shfl_down(v3, sft);
        float tc = __shfl_down(c, sft);
        if (lane + sft < 64 && go == g) {
            v0 += t0; v1 += t1; v2 += t2; v3 += t3; c += tc;
        }
    }
    int gp = __shfl_up(g, 1);
    bool head = (lane == 0) || (gp != g);
    if (g >= 0 && head) {
        unsafeAtomicAdd(&gsum[g * 4 + 0], v0);
        unsafeAtomicAdd(&gsum[g * 4 + 1], v1);
        unsafeAtomicAdd(&gsum[g * 4 + 2], v2);
        unsafeAtomicAdd(&gsum[g * 4 + 3], v3);
        unsafeAtomicAdd(&gcnt[g], c);
    }
}

__global__ void k_final(const float* __restrict__ gsum, const float* __restrict__ gcnt,
                        const float* __restrict__ Wo, const float* __restrict__ bo,
                        float* __restrict__ out, int n_graphs) {
    int i = blockIdx.x * blockDim.x + threadIdx.x;
    if (i >= n_graphs) return;
    float inv = 1.0f / fmaxf(gcnt[i], 1.0f);
    float z = bo[0];
#pragma unroll
    for (int j = 0; j < 4; ++j) z = fmaf(gsum[i * 4 + j] * inv, Wo[j], z);
    out[i] = 1.0f / (1.0f + expf(-z));
}

extern "C" void kernel_launch(void* const* d_in, const int* in_sizes, int n_in,
                              void* d_out, int out_size, void* d_ws, size_t ws_size,
                              hipStream_t stream) {
    const float* feat = (const float*)d_in[0];
    const int*   src  = (const int*)d_in[1];
    const int*   dst  = (const int*)d_in[2];
    const int*   gid  = (const int*)d_in[3];
    const float* W1   = (const float*)d_in[4];
    const float* b1   = (const float*)d_in[5];
    const float* W2   = (const float*)d_in[6];
    const float* b2   = (const float*)d_in[7];
    const float* Wo   = (const float*)d_in[8];
    const float* bo   = (const float*)d_in[9];
    float* out = (float*)d_out;

    const int n_nodes  = in_sizes[0] / 10;
    const int n_edges  = in_sizes[1];
    const int n_graphs = out_size;
    const int nbk_used = (n_nodes + (1 << BSHIFT) - 1) >> BSHIFT;

    unsigned int* ws32 = (unsigned int*)d_ws;
    const size_t PDW = (size_t)NBKT * CAP;
    const size_t n = (size_t)n_nodes;
    unsigned int*   pd     = ws32;
    unsigned short* ps     = (unsigned short*)ws32;        // aliases pd (time-muxed)
    unsigned int*   cs     = ws32 + PDW;
    unsigned int*   cd     = cs + NBKT;
    float*          gsum   = (float*)(cd + NBKT);
    float*          gcnt   = gsum + 4 * (size_t)n_graphs;
    float*          onorm  = gcnt + n_graphs;              // [n]
    unsigned int*   starts = (unsigned int*)(onorm + n);   // [NBKT*1024]
    unsigned int*   y1     = starts + (size_t)NBKT * 1024; // [2n] dw, 8B aligned
    unsigned int*   y2     = y1 + 2 * n;                   // [n] dw

    (void)hipMemsetAsync(cs, 0, (2 * NBKT + 5 * (size_t)n_graphs) * sizeof(unsigned int),
                         stream);

    const int nchunk = (n_edges + CHUNK - 1) / CHUNK;
    const int B = 256;

    k_part_src<<<nchunk, PTH, 0, stream>>>(src, ps, cs, n_edges);
    k_deg_src<<<nbk_used, 512, 0, stream>>>(ps, cs, onorm, n_nodes);
    k_part_dst<<<nchunk, PTH, 0, stream>>>(src, dst, pd, cd, n_edges);
    k_sort_dst<<<nbk_used, 512, 0, stream>>>(pd, cd, starts);
    k_node1<<<(n_nodes + B - 1) / B, B, 0, stream>>>(feat, W1, onorm, (uint2*)y1, n_nodes);
    k_agg1<<<nbk_used, 1024, 0, stream>>>(pd, cd, starts, (const uint2*)y1, b1, W2, onorm,
                                          y2, n_nodes);
    k_agg2<<<nbk_used, 1024, 0, stream>>>(pd, cd, starts, y2, b2, gid, gsum, gcnt, n_nodes);
    k_final<<<(n_graphs + B - 1) / B, B, 0, stream>>>(gsum, gcnt, Wo, bo, out, n_graphs);
}